// Round 3
// baseline (1567.025 us; speedup 1.0000x reference)
//
#include <hip/hip_runtime.h>
#include <math.h>

typedef float f32x4 __attribute__((ext_vector_type(4)));
typedef short bf16x8 __attribute__((ext_vector_type(8)));
typedef unsigned short u16;
typedef unsigned int u32;
typedef unsigned long long u64;

__device__ __forceinline__ float bf2f(u16 v) {
    union { unsigned u; float f; } x; x.u = ((unsigned)v) << 16; return x.f;
}
__device__ __forceinline__ u16 f2bf(float f) {
    union { float f; unsigned u; } x; x.f = f;
    unsigned r = x.u + 0x7fff + ((x.u >> 16) & 1);   // RNE
    return (u16)(r >> 16);
}

// async global->LDS, 16B per lane. LDS dest must be wave-uniform base; HW adds lane*16.
__device__ __forceinline__ void gload_lds16(const u16* g, u16* l) {
    __builtin_amdgcn_global_load_lds(
        (const __attribute__((address_space(1))) void*)g,
        (__attribute__((address_space(3))) void*)l, 16, 0, 0);
}

// ---------------- embedding gather:  xb[t*16+b][e] = bf16(emb[sentence[b][t]][e])
__global__ void gather_embed(const int* __restrict__ sent, const float* __restrict__ emb,
                             u16* __restrict__ xb) {
    int row = blockIdx.x;             // t*16 + b
    int t = row >> 4, b = row & 15;
    int idx = sent[b * 128 + t];
    float4 v = ((const float4*)(emb + (size_t)idx * 512))[threadIdx.x];
    ushort4 s = { f2bf(v.x), f2bf(v.y), f2bf(v.z), f2bf(v.w) };
    ((ushort4*)(xb + (size_t)row * 512))[threadIdx.x] = s;
}

// ---------------- concat biases: b4[g*1024+c] = b_g[c]
__global__ void build_b4(const float* __restrict__ bi, const float* __restrict__ bf_,
                         const float* __restrict__ bo, const float* __restrict__ bc,
                         float* __restrict__ b4) {
    int i = blockIdx.x * 256 + threadIdx.x;   // 4096
    const float* p = (i < 1024) ? bi : (i < 2048) ? bf_ : (i < 3072) ? bo : bc;
    b4[i] = p[i & 1023];
}

// ---------------- tiled transpose + fp32->bf16:  out[C][R] = bf16(in[R][C])
__global__ void transpose_cvt(const float* __restrict__ in, int ldin,
                              u16* __restrict__ out, int ldout) {
    __shared__ float tile[32][33];
    int rt = blockIdx.y * 32, ct = blockIdx.x * 32;
    int tid = threadIdx.x;
    int r = tid >> 3, cq = (tid & 7) * 4;
    float4 v = *(const float4*)(in + (size_t)(rt + r) * ldin + ct + cq);
    tile[r][cq] = v.x; tile[r][cq + 1] = v.y; tile[r][cq + 2] = v.z; tile[r][cq + 3] = v.w;
    __syncthreads();
    int c = tid >> 3, rq = (tid & 7) * 4;
    ushort4 s = { f2bf(tile[rq][c]), f2bf(tile[rq + 1][c]),
                  f2bf(tile[rq + 2][c]), f2bf(tile[rq + 3][c]) };
    *(ushort4*)(out + (size_t)(ct + c) * ldout + rt + rq) = s;
}

// ---------------- GEMM: C = A[M][K](bf16) @ Bt[N][K](bf16)^T + bias
// MODE 0: A row-major, C row-major [M][4096] f32 (xz).
// MODE 1: A row r of tile = hs row (r*16 + blockIdx.x)  [b-major tiles];
//         out[b][v][t] f32 with float4 stores along t (coalesced).
template <int MODE>
__global__ __launch_bounds__(256) void gemm_bt(
    const u16* __restrict__ A, const u16* __restrict__ Bt,
    const float* __restrict__ bias, float* __restrict__ C, int K) {
    const int tid = threadIdx.x;
    const int l = tid & 63, w = tid >> 6;
    const int wr = w >> 1, wc = w & 1;
    const int m0 = blockIdx.x * 128, n0 = blockIdx.y * 128;
    __shared__ __align__(16) u16 As[128 * 64];
    __shared__ __align__(16) u16 Bs[128 * 64];

    f32x4 acc[4][4];
    f32x4 zz = { 0.f, 0.f, 0.f, 0.f };
#pragma unroll
    for (int i = 0; i < 4; i++)
#pragma unroll
        for (int j = 0; j < 4; j++) acc[i][j] = zz;

    const int nkt = K >> 6;
    for (int kt = 0; kt < nkt; ++kt) {
        __syncthreads();   // previous compute done before overwrite
#pragma unroll
        for (int i = 0; i < 4; i++) {
            int cbase = i * 256 + w * 64;      // wave-uniform LDS base (elements/8)
            int c = cbase + l, row = c >> 3, kc = c & 7;
            int arow = (MODE == 1) ? (row * 16 + (int)blockIdx.x) : (m0 + row);
            gload_lds16(A + (size_t)arow * K + kt * 64 + kc * 8, As + (size_t)cbase * 8);
            gload_lds16(Bt + (size_t)(n0 + row) * K + kt * 64 + kc * 8, Bs + (size_t)cbase * 8);
        }
        __syncthreads();   // drains vmcnt -> LDS ready
#pragma unroll
        for (int kk = 0; kk < 2; kk++) {
            bf16x8 af[4], bfv[4];
#pragma unroll
            for (int mi = 0; mi < 4; mi++)
                af[mi] = *(const bf16x8*)(As + (wr * 64 + mi * 16 + (l & 15)) * 64 + kk * 32 + (l >> 4) * 8);
#pragma unroll
            for (int ni = 0; ni < 4; ni++)
                bfv[ni] = *(const bf16x8*)(Bs + (wc * 64 + ni * 16 + (l & 15)) * 64 + kk * 32 + (l >> 4) * 8);
#pragma unroll
            for (int mi = 0; mi < 4; mi++)
#pragma unroll
                for (int ni = 0; ni < 4; ni++)
                    acc[mi][ni] = __builtin_amdgcn_mfma_f32_16x16x32_bf16(af[mi], bfv[ni], acc[mi][ni], 0, 0, 0);
        }
    }
    const int lr = l >> 4, lc = l & 15;
#pragma unroll
    for (int ni = 0; ni < 4; ni++) {
        int col = n0 + wc * 64 + ni * 16 + lc;
        float bv = bias[col];
#pragma unroll
        for (int mi = 0; mi < 4; mi++) {
            if (MODE == 0) {
#pragma unroll
                for (int r = 0; r < 4; r++) {
                    int row = m0 + wr * 64 + mi * 16 + lr * 4 + r;
                    C[(size_t)row * 4096 + col] = acc[mi][ni][r] + bv;
                }
            } else {
                int t0 = wr * 64 + mi * 16 + lr * 4;     // 4 consecutive t
                float4 st = { acc[mi][ni][0] + bv, acc[mi][ni][1] + bv,
                              acc[mi][ni][2] + bv, acc[mi][ni][3] + bv };
                *(float4*)(C + (size_t)blockIdx.x * 4096000 + (size_t)col * 128 + t0) = st;
            }
        }
    }
}

// ---------------- persistent LSTM recurrence: 64 WGs, each owns 16 h-cols.
// Per-(step,WG) one-shot readiness flags replace the global barrier:
//  - forward-only dependency (no backward wait; h/flag buffers are per-step)
//  - plain relaxed system stores (no serialized RMW at the LLC)
//  - each wave polls independently (64 parallel 4B loads + ballot)
__global__ __launch_bounds__(256, 1) void lstm_rec(
    u16* __restrict__ hs,          // [128*16][1024] bf16, row = t*16+b
    const float* __restrict__ xz,  // [128*16][4096] f32 (x-part + bias, precomputed)
    const float* __restrict__ Wi, const float* __restrict__ Wf,
    const float* __restrict__ Wo, const float* __restrict__ Wc,
    u32* __restrict__ flags) {     // [128][64], zeroed before launch
    __shared__ __align__(16) u16 whf[4][32][64][8];   // 128 KiB: [gate][k-chunk][lane][8 bf16]
    __shared__ float zlds[4][16][17];
    const int j = blockIdx.x;            // h-col group: cols [j*16, j*16+16)
    const int tid = threadIdx.x;
    const int w = tid >> 6, l = tid & 63;
    const float* Wg = (w == 0) ? Wi : (w == 1) ? Wf : (w == 2) ? Wo : Wc;

    // Fill B-fragments: lane l holds W_h[kk*32 + 8*(l>>4)+e][j*16 + (l&15)]
    {
        const int lc = l & 15, lh = l >> 4;
        for (int kk = 0; kk < 32; ++kk)
#pragma unroll
            for (int e = 0; e < 8; ++e) {
                int k = kk * 32 + lh * 8 + e;
                whf[w][kk][l][e] = f2bf(Wg[(size_t)(512 + k) * 1024 + j * 16 + lc]);
            }
    }
    __syncthreads();

    const int b = tid >> 4, hc = tid & 15;
    float cst = 0.f;
    const float* xr0 = xz + (size_t)b * 4096 + j * 16 + hc;
    float pzi = xr0[0], pzf = xr0[1024], pzo = xr0[2048], pzc = xr0[3072];

    for (int t = 0; t < 128; ++t) {
        if (t > 0) {
            // ---- poll step-(t-1) readiness flags (each wave independently)
            int spins = 0;
            while (true) {
                u32 f = __hip_atomic_load(&flags[(t - 1) * 64 + l],
                                          __ATOMIC_RELAXED, __HIP_MEMORY_SCOPE_SYSTEM);
                if (__ballot(f != 0) == ~0ull) break;
                if (++spins > (1 << 20)) break;   // safety bail: no infinite hang
            }
            // ---- wave w computes gate w's 16x16 z-tile: z = h_{t-1} @ Wh_slice
            const u16* hrow = hs + (size_t)((t - 1) * 16 + (l & 15)) * 1024;
            bf16x8 a[32];
#pragma unroll
            for (int kk = 0; kk < 32; ++kk) {
                const u16* p = hrow + kk * 32 + (l >> 4) * 8;
                union { u64 q[2]; bf16x8 v; } u;
                u.q[0] = __hip_atomic_load((const u64*)p, __ATOMIC_RELAXED, __HIP_MEMORY_SCOPE_SYSTEM);
                u.q[1] = __hip_atomic_load((const u64*)(p + 4), __ATOMIC_RELAXED, __HIP_MEMORY_SCOPE_SYSTEM);
                a[kk] = u.v;
            }
            f32x4 zv = { 0.f, 0.f, 0.f, 0.f };
            f32x4 ac0 = zv, ac1 = zv, ac2 = zv, ac3 = zv;
#pragma unroll
            for (int kk = 0; kk < 32; kk += 4) {
                ac0 = __builtin_amdgcn_mfma_f32_16x16x32_bf16(a[kk + 0], *(const bf16x8*)&whf[w][kk + 0][l][0], ac0, 0, 0, 0);
                ac1 = __builtin_amdgcn_mfma_f32_16x16x32_bf16(a[kk + 1], *(const bf16x8*)&whf[w][kk + 1][l][0], ac1, 0, 0, 0);
                ac2 = __builtin_amdgcn_mfma_f32_16x16x32_bf16(a[kk + 2], *(const bf16x8*)&whf[w][kk + 2][l][0], ac2, 0, 0, 0);
                ac3 = __builtin_amdgcn_mfma_f32_16x16x32_bf16(a[kk + 3], *(const bf16x8*)&whf[w][kk + 3][l][0], ac3, 0, 0, 0);
            }
            f32x4 acc = (ac0 + ac1) + (ac2 + ac3);
#pragma unroll
            for (int r = 0; r < 4; ++r)
                zlds[w][(l >> 4) * 4 + r][l & 15] = acc[r];
        }
        __syncthreads();
        {
            float zi = pzi, zf = pzf, zo = pzo, zc = pzc;
            if (t > 0) {
                zi += zlds[0][b][hc]; zf += zlds[1][b][hc];
                zo += zlds[2][b][hc]; zc += zlds[3][b][hc];
            }
            float ig = 1.f / (1.f + __expf(-zi));
            float fg = 1.f / (1.f + __expf(-zf));
            float og = 1.f / (1.f + __expf(-zo));
            float gg = tanhf(zc);
            cst = fg * cst + ig * gg;
            float h = og * tanhf(cst);
            float hn = __shfl_xor(h, 1);          // partner lane's h (hc^1)
            if (!(l & 1)) {                        // even hc stores packed pair
                unsigned pk = (unsigned)f2bf(h) | ((unsigned)f2bf(hn) << 16);
                u32* dst = (u32*)hs + (((size_t)(t * 16 + b) * 1024 + j * 16 + hc) >> 1);
                __hip_atomic_store(dst, pk, __ATOMIC_RELAXED, __HIP_MEMORY_SCOPE_SYSTEM);
            }
            if (t < 127) {   // prefetch next xz (L2-cached plain loads)
                const float* xr = xz + (size_t)((t + 1) * 16 + b) * 4096 + j * 16 + hc;
                pzi = xr[0]; pzf = xr[1024]; pzo = xr[2048]; pzc = xr[3072];
            }
        }
        __syncthreads();   // each wave's s_waitcnt vmcnt(0): h stores at coherence point
        if (tid == 0)      // publish readiness (plain store, own word -> no RMW serialization)
            __hip_atomic_store(&flags[t * 64 + j], 1u,
                               __ATOMIC_RELAXED, __HIP_MEMORY_SCOPE_SYSTEM);
    }
}

extern "C" void kernel_launch(void* const* d_in, const int* in_sizes, int n_in,
                              void* d_out, int out_size, void* d_ws, size_t ws_size,
                              hipStream_t stream) {
    const int*   sent = (const int*)d_in[0];
    const float* emb  = (const float*)d_in[1];
    const float* W_i  = (const float*)d_in[2];
    const float* b_i  = (const float*)d_in[3];
    const float* W_f  = (const float*)d_in[4];
    const float* b_f  = (const float*)d_in[5];
    const float* W_o  = (const float*)d_in[6];
    const float* b_o  = (const float*)d_in[7];
    const float* W_c  = (const float*)d_in[8];
    const float* b_c  = (const float*)d_in[9];
    const float* W_hq = (const float*)d_in[10];
    const float* b_q  = (const float*)d_in[11];
    float* out = (float*)d_out;

    char* ws = (char*)d_ws;
    size_t off = 0;
    auto alloc = [&](size_t bytes) { void* p = ws + off; off += (bytes + 255) & ~255ull; return p; };
    u32*   flags = (u32*)alloc((size_t)128 * 64 * 4);
    float* b4   = (float*)alloc((size_t)4096 * 4);
    u16*   xb   = (u16*)alloc((size_t)2048 * 512 * 2);
    u16*   wxt  = (u16*)alloc((size_t)4096 * 512 * 2);
    u16*   hs   = (u16*)alloc((size_t)2048 * 1024 * 2);
    float* xz   = (float*)alloc((size_t)2048 * 4096 * 4);
    u16*   whqt = (u16*)alloc((size_t)32000 * 1024 * 2);

    hipMemsetAsync(flags, 0, (size_t)128 * 64 * 4, stream);
    gather_embed<<<2048, 128, 0, stream>>>(sent, emb, xb);
    build_b4<<<16, 256, 0, stream>>>(b_i, b_f, b_o, b_c, b4);
    transpose_cvt<<<dim3(32, 16), 256, 0, stream>>>(W_i, 1024, wxt + (size_t)0 * 1024 * 512, 512);
    transpose_cvt<<<dim3(32, 16), 256, 0, stream>>>(W_f, 1024, wxt + (size_t)1 * 1024 * 512, 512);
    transpose_cvt<<<dim3(32, 16), 256, 0, stream>>>(W_o, 1024, wxt + (size_t)2 * 1024 * 512, 512);
    transpose_cvt<<<dim3(32, 16), 256, 0, stream>>>(W_c, 1024, wxt + (size_t)3 * 1024 * 512, 512);
    transpose_cvt<<<dim3(1000, 32), 256, 0, stream>>>(W_hq, 32000, whqt, 1024);
    // xz = X @ Wx + b4 : M=2048, K=512, N=4096
    gemm_bt<0><<<dim3(16, 32), 256, 0, stream>>>(xb, wxt, b4, xz, 512);
    // recurrence (writes hs)
    lstm_rec<<<64, 256, 0, stream>>>(hs, xz, W_i, W_f, W_o, W_c, flags);
    // out[b][v][t] = hs @ W_hq + b_q : M=2048 (b-major tiles), K=1024, N=32000
    gemm_bt<1><<<dim3(16, 250), 256, 0, stream>>>(hs, whqt, b_q, out, 1024);
}

// Round 4
// 1117.552 us; speedup vs baseline: 1.4022x; 1.4022x over previous
//
#include <hip/hip_runtime.h>
#include <math.h>

typedef float f32x4 __attribute__((ext_vector_type(4)));
typedef short bf16x8 __attribute__((ext_vector_type(8)));
typedef unsigned short u16;
typedef unsigned int u32;
typedef unsigned long long u64;

__device__ __forceinline__ float bf2f(u16 v) {
    union { unsigned u; float f; } x; x.u = ((unsigned)v) << 16; return x.f;
}
__device__ __forceinline__ u16 f2bf(float f) {
    union { float f; unsigned u; } x; x.f = f;
    unsigned r = x.u + 0x7fff + ((x.u >> 16) & 1);   // RNE
    return (u16)(r >> 16);
}

// async global->LDS, 16B per lane. LDS dest must be wave-uniform base; HW adds lane*16.
__device__ __forceinline__ void gload_lds16(const u16* g, u16* l) {
    __builtin_amdgcn_global_load_lds(
        (const __attribute__((address_space(1))) void*)g,
        (__attribute__((address_space(3))) void*)l, 16, 0, 0);
}

// ---------------- embedding gather:  xb[t*16+b][e] = bf16(emb[sentence[b][t]][e])
__global__ void gather_embed(const int* __restrict__ sent, const float* __restrict__ emb,
                             u16* __restrict__ xb) {
    int row = blockIdx.x;             // t*16 + b
    int t = row >> 4, b = row & 15;
    int idx = sent[b * 128 + t];
    float4 v = ((const float4*)(emb + (size_t)idx * 512))[threadIdx.x];
    ushort4 s = { f2bf(v.x), f2bf(v.y), f2bf(v.z), f2bf(v.w) };
    ((ushort4*)(xb + (size_t)row * 512))[threadIdx.x] = s;
}

// ---------------- concat biases: b4[g*1024+c] = b_g[c]
__global__ void build_b4(const float* __restrict__ bi, const float* __restrict__ bf_,
                         const float* __restrict__ bo, const float* __restrict__ bc,
                         float* __restrict__ b4) {
    int i = blockIdx.x * 256 + threadIdx.x;   // 4096
    const float* p = (i < 1024) ? bi : (i < 2048) ? bf_ : (i < 3072) ? bo : bc;
    b4[i] = p[i & 1023];
}

// ---------------- tiled transpose + fp32->bf16:  out[C][R] = bf16(in[R][C])
__global__ void transpose_cvt(const float* __restrict__ in, int ldin,
                              u16* __restrict__ out, int ldout) {
    __shared__ float tile[32][33];
    int rt = blockIdx.y * 32, ct = blockIdx.x * 32;
    int tid = threadIdx.x;
    int r = tid >> 3, cq = (tid & 7) * 4;
    float4 v = *(const float4*)(in + (size_t)(rt + r) * ldin + ct + cq);
    tile[r][cq] = v.x; tile[r][cq + 1] = v.y; tile[r][cq + 2] = v.z; tile[r][cq + 3] = v.w;
    __syncthreads();
    int c = tid >> 3, rq = (tid & 7) * 4;
    ushort4 s = { f2bf(tile[rq][c]), f2bf(tile[rq + 1][c]),
                  f2bf(tile[rq + 2][c]), f2bf(tile[rq + 3][c]) };
    *(ushort4*)(out + (size_t)(ct + c) * ldout + rt + rq) = s;
}

// ---------------- GEMM: C = A[M][K](bf16) @ Bt[N][K](bf16)^T + bias
// MODE 0: A row-major, C row-major [M][4096] f32 (xz).
// MODE 1: A row r of tile = hs row (r*16 + blockIdx.x)  [b-major tiles];
//         out[b][v][t] f32 with float4 stores along t (coalesced).
template <int MODE>
__global__ __launch_bounds__(256) void gemm_bt(
    const u16* __restrict__ A, const u16* __restrict__ Bt,
    const float* __restrict__ bias, float* __restrict__ C, int K) {
    const int tid = threadIdx.x;
    const int l = tid & 63, w = tid >> 6;
    const int wr = w >> 1, wc = w & 1;
    const int m0 = blockIdx.x * 128, n0 = blockIdx.y * 128;
    __shared__ __align__(16) u16 As[128 * 64];
    __shared__ __align__(16) u16 Bs[128 * 64];

    f32x4 acc[4][4];
    f32x4 zz = { 0.f, 0.f, 0.f, 0.f };
#pragma unroll
    for (int i = 0; i < 4; i++)
#pragma unroll
        for (int j = 0; j < 4; j++) acc[i][j] = zz;

    const int nkt = K >> 6;
    for (int kt = 0; kt < nkt; ++kt) {
        __syncthreads();   // previous compute done before overwrite
#pragma unroll
        for (int i = 0; i < 4; i++) {
            int cbase = i * 256 + w * 64;      // wave-uniform LDS base (elements/8)
            int c = cbase + l, row = c >> 3, kc = c & 7;
            int arow = (MODE == 1) ? (row * 16 + (int)blockIdx.x) : (m0 + row);
            gload_lds16(A + (size_t)arow * K + kt * 64 + kc * 8, As + (size_t)cbase * 8);
            gload_lds16(Bt + (size_t)(n0 + row) * K + kt * 64 + kc * 8, Bs + (size_t)cbase * 8);
        }
        __syncthreads();   // drains vmcnt -> LDS ready
#pragma unroll
        for (int kk = 0; kk < 2; kk++) {
            bf16x8 af[4], bfv[4];
#pragma unroll
            for (int mi = 0; mi < 4; mi++)
                af[mi] = *(const bf16x8*)(As + (wr * 64 + mi * 16 + (l & 15)) * 64 + kk * 32 + (l >> 4) * 8);
#pragma unroll
            for (int ni = 0; ni < 4; ni++)
                bfv[ni] = *(const bf16x8*)(Bs + (wc * 64 + ni * 16 + (l & 15)) * 64 + kk * 32 + (l >> 4) * 8);
#pragma unroll
            for (int mi = 0; mi < 4; mi++)
#pragma unroll
                for (int ni = 0; ni < 4; ni++)
                    acc[mi][ni] = __builtin_amdgcn_mfma_f32_16x16x32_bf16(af[mi], bfv[ni], acc[mi][ni], 0, 0, 0);
        }
    }
    const int lr = l >> 4, lc = l & 15;
#pragma unroll
    for (int ni = 0; ni < 4; ni++) {
        int col = n0 + wc * 64 + ni * 16 + lc;
        float bv = bias[col];
#pragma unroll
        for (int mi = 0; mi < 4; mi++) {
            if (MODE == 0) {
#pragma unroll
                for (int r = 0; r < 4; r++) {
                    int row = m0 + wr * 64 + mi * 16 + lr * 4 + r;
                    C[(size_t)row * 4096 + col] = acc[mi][ni][r] + bv;
                }
            } else {
                int t0 = wr * 64 + mi * 16 + lr * 4;     // 4 consecutive t
                float4 st = { acc[mi][ni][0] + bv, acc[mi][ni][1] + bv,
                              acc[mi][ni][2] + bv, acc[mi][ni][3] + bv };
                *(float4*)(C + (size_t)blockIdx.x * 4096000 + (size_t)col * 128 + t0) = st;
            }
        }
    }
}

// ---------------- persistent LSTM recurrence: 64 WGs, each owns 16 h-cols.
// Protocol per step t:
//   writers: h stores system-scope (write-through to LLC) -> barrier (vmcnt drain)
//            -> flag[t][j]=1 (plain relaxed system store, own word)
//   readers: ONE wave polls the 64 flags of t-1 (s_sleep backoff) -> barrier ->
//            h loads are PLAIN CACHED loads (demand-miss post-flag -> fresh LLC copy;
//            each line fetched ~once per XCD L2 instead of once per wave).
// Cross-replay staleness (L1/L2 lines from a previous graph replay) is killed by a
// one-time agent-scope acquire fence (buffer_inv) at kernel entry.
__global__ __launch_bounds__(256, 1) void lstm_rec(
    u16* __restrict__ hs,          // [128*16][1024] bf16, row = t*16+b
    const float* __restrict__ xz,  // [128*16][4096] f32 (x-part + bias, precomputed)
    const float* __restrict__ Wi, const float* __restrict__ Wf,
    const float* __restrict__ Wo, const float* __restrict__ Wc,
    u32* __restrict__ flags) {     // [128][64] + 64 dummies, zeroed before launch
    __shared__ __align__(16) u16 whf[4][32][64][8];   // 128 KiB: [gate][k-chunk][lane][8 bf16]
    __shared__ float zlds[4][16][17];
    const int j = blockIdx.x;            // h-col group: cols [j*16, j*16+16)
    const int tid = threadIdx.x;
    const int w = tid >> 6, l = tid & 63;
    const float* Wg = (w == 0) ? Wi : (w == 1) ? Wf : (w == 2) ? Wo : Wc;

    // One-time cache invalidate (L1 of this CU + L2 of this XCD): acquire RMW, agent scope.
    if (tid == 0)
        __hip_atomic_fetch_add(&flags[128 * 64 + j], 0u,
                               __ATOMIC_ACQ_REL, __HIP_MEMORY_SCOPE_AGENT);
    __syncthreads();

    // Fill B-fragments: lane l holds W_h[kk*32 + 8*(l>>4)+e][j*16 + (l&15)]
    {
        const int lc = l & 15, lh = l >> 4;
        for (int kk = 0; kk < 32; ++kk)
#pragma unroll
            for (int e = 0; e < 8; ++e) {
                int k = kk * 32 + lh * 8 + e;
                whf[w][kk][l][e] = f2bf(Wg[(size_t)(512 + k) * 1024 + j * 16 + lc]);
            }
    }
    __syncthreads();

    const int b = tid >> 4, hc = tid & 15;
    float cst = 0.f;
    const float* xr0 = xz + (size_t)b * 4096 + j * 16 + hc;
    float pzi = xr0[0], pzf = xr0[1024], pzo = xr0[2048], pzc = xr0[3072];

    for (int t = 0; t < 128; ++t) {
        if (t > 0) {
            // ---- one wave polls step-(t-1) readiness flags with backoff
            if (w == 0) {
                int spins = 0;
                while (true) {
                    u32 f = __hip_atomic_load(&flags[(t - 1) * 64 + l],
                                              __ATOMIC_RELAXED, __HIP_MEMORY_SCOPE_SYSTEM);
                    if (__ballot(f != 0) == ~0ull) break;
                    __builtin_amdgcn_s_sleep(2);
                    if (++spins > (1 << 20)) break;   // safety bail
                }
            }
            __syncthreads();   // all waves gated on flags
            // ---- wave w computes gate w's 16x16 z-tile: z = h_{t-1} @ Wh_slice
            // plain cached loads: post-flag demand fetch, served by L1/L2 after first touch
            const u16* hrow = hs + (size_t)((t - 1) * 16 + (l & 15)) * 1024;
            bf16x8 a[32];
#pragma unroll
            for (int kk = 0; kk < 32; ++kk)
                a[kk] = *(const bf16x8*)(hrow + kk * 32 + (l >> 4) * 8);
            f32x4 zv = { 0.f, 0.f, 0.f, 0.f };
            f32x4 ac0 = zv, ac1 = zv, ac2 = zv, ac3 = zv;
#pragma unroll
            for (int kk = 0; kk < 32; kk += 4) {
                ac0 = __builtin_amdgcn_mfma_f32_16x16x32_bf16(a[kk + 0], *(const bf16x8*)&whf[w][kk + 0][l][0], ac0, 0, 0, 0);
                ac1 = __builtin_amdgcn_mfma_f32_16x16x32_bf16(a[kk + 1], *(const bf16x8*)&whf[w][kk + 1][l][0], ac1, 0, 0, 0);
                ac2 = __builtin_amdgcn_mfma_f32_16x16x32_bf16(a[kk + 2], *(const bf16x8*)&whf[w][kk + 2][l][0], ac2, 0, 0, 0);
                ac3 = __builtin_amdgcn_mfma_f32_16x16x32_bf16(a[kk + 3], *(const bf16x8*)&whf[w][kk + 3][l][0], ac3, 0, 0, 0);
            }
            f32x4 acc = (ac0 + ac1) + (ac2 + ac3);
#pragma unroll
            for (int r = 0; r < 4; ++r)
                zlds[w][(l >> 4) * 4 + r][l & 15] = acc[r];
        }
        __syncthreads();
        {
            float zi = pzi, zf = pzf, zo = pzo, zc = pzc;
            if (t > 0) {
                zi += zlds[0][b][hc]; zf += zlds[1][b][hc];
                zo += zlds[2][b][hc]; zc += zlds[3][b][hc];
            }
            float ig = 1.f / (1.f + __expf(-zi));
            float fg = 1.f / (1.f + __expf(-zf));
            float og = 1.f / (1.f + __expf(-zo));
            float gg = tanhf(zc);
            cst = fg * cst + ig * gg;
            float h = og * tanhf(cst);
            float hn = __shfl_xor(h, 1);          // partner lane's h (hc^1)
            if (!(l & 1)) {                        // even hc stores packed pair
                unsigned pk = (unsigned)f2bf(h) | ((unsigned)f2bf(hn) << 16);
                u32* dst = (u32*)hs + (((size_t)(t * 16 + b) * 1024 + j * 16 + hc) >> 1);
                __hip_atomic_store(dst, pk, __ATOMIC_RELAXED, __HIP_MEMORY_SCOPE_SYSTEM);
            }
            if (t < 127) {   // prefetch next xz (L2-cached plain loads)
                const float* xr = xz + (size_t)((t + 1) * 16 + b) * 4096 + j * 16 + hc;
                pzi = xr[0]; pzf = xr[1024]; pzo = xr[2048]; pzc = xr[3072];
            }
        }
        __syncthreads();   // each wave's s_waitcnt vmcnt(0): h stores at coherence point
        if (tid == 0)      // publish readiness (plain store, own word -> no RMW serialization)
            __hip_atomic_store(&flags[t * 64 + j], 1u,
                               __ATOMIC_RELAXED, __HIP_MEMORY_SCOPE_SYSTEM);
    }
}

extern "C" void kernel_launch(void* const* d_in, const int* in_sizes, int n_in,
                              void* d_out, int out_size, void* d_ws, size_t ws_size,
                              hipStream_t stream) {
    const int*   sent = (const int*)d_in[0];
    const float* emb  = (const float*)d_in[1];
    const float* W_i  = (const float*)d_in[2];
    const float* b_i  = (const float*)d_in[3];
    const float* W_f  = (const float*)d_in[4];
    const float* b_f  = (const float*)d_in[5];
    const float* W_o  = (const float*)d_in[6];
    const float* b_o  = (const float*)d_in[7];
    const float* W_c  = (const float*)d_in[8];
    const float* b_c  = (const float*)d_in[9];
    const float* W_hq = (const float*)d_in[10];
    const float* b_q  = (const float*)d_in[11];
    float* out = (float*)d_out;

    char* ws = (char*)d_ws;
    size_t off = 0;
    auto alloc = [&](size_t bytes) { void* p = ws + off; off += (bytes + 255) & ~255ull; return p; };
    u32*   flags = (u32*)alloc((size_t)(128 * 64 + 64) * 4);
    float* b4   = (float*)alloc((size_t)4096 * 4);
    u16*   xb   = (u16*)alloc((size_t)2048 * 512 * 2);
    u16*   wxt  = (u16*)alloc((size_t)4096 * 512 * 2);
    u16*   hs   = (u16*)alloc((size_t)2048 * 1024 * 2);
    float* xz   = (float*)alloc((size_t)2048 * 4096 * 4);
    u16*   whqt = (u16*)alloc((size_t)32000 * 1024 * 2);

    hipMemsetAsync(flags, 0, (size_t)(128 * 64 + 64) * 4, stream);
    gather_embed<<<2048, 128, 0, stream>>>(sent, emb, xb);
    build_b4<<<16, 256, 0, stream>>>(b_i, b_f, b_o, b_c, b4);
    transpose_cvt<<<dim3(32, 16), 256, 0, stream>>>(W_i, 1024, wxt + (size_t)0 * 1024 * 512, 512);
    transpose_cvt<<<dim3(32, 16), 256, 0, stream>>>(W_f, 1024, wxt + (size_t)1 * 1024 * 512, 512);
    transpose_cvt<<<dim3(32, 16), 256, 0, stream>>>(W_o, 1024, wxt + (size_t)2 * 1024 * 512, 512);
    transpose_cvt<<<dim3(32, 16), 256, 0, stream>>>(W_c, 1024, wxt + (size_t)3 * 1024 * 512, 512);
    transpose_cvt<<<dim3(1000, 32), 256, 0, stream>>>(W_hq, 32000, whqt, 1024);
    // xz = X @ Wx + b4 : M=2048, K=512, N=4096
    gemm_bt<0><<<dim3(16, 32), 256, 0, stream>>>(xb, wxt, b4, xz, 512);
    // recurrence (writes hs)
    lstm_rec<<<64, 256, 0, stream>>>(hs, xz, W_i, W_f, W_o, W_c, flags);
    // out[b][v][t] = hs @ W_hq + b_q : M=2048 (b-major tiles), K=1024, N=32000
    gemm_bt<1><<<dim3(16, 250), 256, 0, stream>>>(hs, whqt, b_q, out, 1024);
}

// Round 5
// 999.707 us; speedup vs baseline: 1.5675x; 1.1179x over previous
//
#include <hip/hip_runtime.h>
#include <math.h>

typedef float f32x4 __attribute__((ext_vector_type(4)));
typedef short bf16x8 __attribute__((ext_vector_type(8)));
typedef unsigned short u16;
typedef unsigned int u32;
typedef unsigned long long u64;

__device__ __forceinline__ float bf2f(u16 v) {
    union { unsigned u; float f; } x; x.u = ((unsigned)v) << 16; return x.f;
}
__device__ __forceinline__ u16 f2bf(float f) {
    union { float f; unsigned u; } x; x.f = f;
    unsigned r = x.u + 0x7fff + ((x.u >> 16) & 1);   // RNE
    return (u16)(r >> 16);
}

// async global->LDS, 16B per lane. LDS dest must be wave-uniform base; HW adds lane*16.
__device__ __forceinline__ void gload_lds16(const u16* g, u16* l) {
    __builtin_amdgcn_global_load_lds(
        (const __attribute__((address_space(1))) void*)g,
        (__attribute__((address_space(3))) void*)l, 16, 0, 0);
}

// ---------------- embedding gather:  xb[t*16+b][e] = bf16(emb[sentence[b][t]][e])
__global__ void gather_embed(const int* __restrict__ sent, const float* __restrict__ emb,
                             u16* __restrict__ xb) {
    int row = blockIdx.x;             // t*16 + b
    int t = row >> 4, b = row & 15;
    int idx = sent[b * 128 + t];
    float4 v = ((const float4*)(emb + (size_t)idx * 512))[threadIdx.x];
    ushort4 s = { f2bf(v.x), f2bf(v.y), f2bf(v.z), f2bf(v.w) };
    ((ushort4*)(xb + (size_t)row * 512))[threadIdx.x] = s;
}

// ---------------- concat biases: b4[g*1024+c] = b_g[c]
__global__ void build_b4(const float* __restrict__ bi, const float* __restrict__ bf_,
                         const float* __restrict__ bo, const float* __restrict__ bc,
                         float* __restrict__ b4) {
    int i = blockIdx.x * 256 + threadIdx.x;   // 4096
    const float* p = (i < 1024) ? bi : (i < 2048) ? bf_ : (i < 3072) ? bo : bc;
    b4[i] = p[i & 1023];
}

// ---------------- tiled transpose + fp32->bf16:  out[C][R] = bf16(in[R][C])
__global__ void transpose_cvt(const float* __restrict__ in, int ldin,
                              u16* __restrict__ out, int ldout) {
    __shared__ float tile[32][33];
    int rt = blockIdx.y * 32, ct = blockIdx.x * 32;
    int tid = threadIdx.x;
    int r = tid >> 3, cq = (tid & 7) * 4;
    float4 v = *(const float4*)(in + (size_t)(rt + r) * ldin + ct + cq);
    tile[r][cq] = v.x; tile[r][cq + 1] = v.y; tile[r][cq + 2] = v.z; tile[r][cq + 3] = v.w;
    __syncthreads();
    int c = tid >> 3, rq = (tid & 7) * 4;
    ushort4 s = { f2bf(tile[rq][c]), f2bf(tile[rq + 1][c]),
                  f2bf(tile[rq + 2][c]), f2bf(tile[rq + 3][c]) };
    *(ushort4*)(out + (size_t)(ct + c) * ldout + rt + rq) = s;
}

// ---------------- GEMM: C = A[M][K](bf16) @ Bt[N][K](bf16)^T + bias
// MODE 0: A row-major, C row-major [M][4096] f32 (xz).
// MODE 1: A row r of tile = hs row (r*16 + blockIdx.x)  [b-major tiles];
//         out[b][v][t] f32 with float4 stores along t (coalesced).
template <int MODE>
__global__ __launch_bounds__(256) void gemm_bt(
    const u16* __restrict__ A, const u16* __restrict__ Bt,
    const float* __restrict__ bias, float* __restrict__ C, int K) {
    const int tid = threadIdx.x;
    const int l = tid & 63, w = tid >> 6;
    const int wr = w >> 1, wc = w & 1;
    const int m0 = blockIdx.x * 128, n0 = blockIdx.y * 128;
    __shared__ __align__(16) u16 As[128 * 64];
    __shared__ __align__(16) u16 Bs[128 * 64];

    f32x4 acc[4][4];
    f32x4 zz = { 0.f, 0.f, 0.f, 0.f };
#pragma unroll
    for (int i = 0; i < 4; i++)
#pragma unroll
        for (int j = 0; j < 4; j++) acc[i][j] = zz;

    const int nkt = K >> 6;
    for (int kt = 0; kt < nkt; ++kt) {
        __syncthreads();   // previous compute done before overwrite
#pragma unroll
        for (int i = 0; i < 4; i++) {
            int cbase = i * 256 + w * 64;      // wave-uniform LDS base (elements/8)
            int c = cbase + l, row = c >> 3, kc = c & 7;
            int arow = (MODE == 1) ? (row * 16 + (int)blockIdx.x) : (m0 + row);
            gload_lds16(A + (size_t)arow * K + kt * 64 + kc * 8, As + (size_t)cbase * 8);
            gload_lds16(Bt + (size_t)(n0 + row) * K + kt * 64 + kc * 8, Bs + (size_t)cbase * 8);
        }
        __syncthreads();   // drains vmcnt -> LDS ready
#pragma unroll
        for (int kk = 0; kk < 2; kk++) {
            bf16x8 af[4], bfv[4];
#pragma unroll
            for (int mi = 0; mi < 4; mi++)
                af[mi] = *(const bf16x8*)(As + (wr * 64 + mi * 16 + (l & 15)) * 64 + kk * 32 + (l >> 4) * 8);
#pragma unroll
            for (int ni = 0; ni < 4; ni++)
                bfv[ni] = *(const bf16x8*)(Bs + (wc * 64 + ni * 16 + (l & 15)) * 64 + kk * 32 + (l >> 4) * 8);
#pragma unroll
            for (int mi = 0; mi < 4; mi++)
#pragma unroll
                for (int ni = 0; ni < 4; ni++)
                    acc[mi][ni] = __builtin_amdgcn_mfma_f32_16x16x32_bf16(af[mi], bfv[ni], acc[mi][ni], 0, 0, 0);
        }
    }
    const int lr = l >> 4, lc = l & 15;
#pragma unroll
    for (int ni = 0; ni < 4; ni++) {
        int col = n0 + wc * 64 + ni * 16 + lc;
        float bv = bias[col];
#pragma unroll
        for (int mi = 0; mi < 4; mi++) {
            if (MODE == 0) {
#pragma unroll
                for (int r = 0; r < 4; r++) {
                    int row = m0 + wr * 64 + mi * 16 + lr * 4 + r;
                    C[(size_t)row * 4096 + col] = acc[mi][ni][r] + bv;
                }
            } else {
                int t0 = wr * 64 + mi * 16 + lr * 4;     // 4 consecutive t
                float4 st = { acc[mi][ni][0] + bv, acc[mi][ni][1] + bv,
                              acc[mi][ni][2] + bv, acc[mi][ni][3] + bv };
                *(float4*)(C + (size_t)blockIdx.x * 4096000 + (size_t)col * 128 + t0) = st;
            }
        }
    }
}

// ---------------- persistent LSTM recurrence: 64 WGs, each owns 16 h-cols.
// Per-(step,WG) flags, ONE PER 64B CACHE LINE (stride 16 u32) to avoid LLC
// same-line serialization during polling. Writers: system-scope write-through
// h stores -> barrier (vmcnt drain) -> own-line flag store. Readers: one wave
// polls (lane l -> WG l's line) with s_sleep backoff -> barrier -> plain cached
// h loads (demand-miss post-flag gets fresh LLC copy; ~1 fetch per line per XCD).
// Cross-replay L1/L2 staleness killed by one-time agent-scope acquire at entry.
#define FLAG_STRIDE 16
__global__ __launch_bounds__(256, 1) void lstm_rec(
    u16* __restrict__ hs,          // [128*16][1024] bf16, row = t*16+b
    const float* __restrict__ xz,  // [128*16][4096] f32 (x-part + bias, precomputed)
    const float* __restrict__ Wi, const float* __restrict__ Wf,
    const float* __restrict__ Wo, const float* __restrict__ Wc,
    u32* __restrict__ flags) {     // [(128*64 + 64) * FLAG_STRIDE], zeroed
    __shared__ __align__(16) u16 whf[4][32][64][8];   // 128 KiB: [gate][k-chunk][lane][8 bf16]
    __shared__ float zlds[4][16][17];
    const int j = blockIdx.x;            // h-col group: cols [j*16, j*16+16)
    const int tid = threadIdx.x;
    const int w = tid >> 6, l = tid & 63;
    const float* Wg = (w == 0) ? Wi : (w == 1) ? Wf : (w == 2) ? Wo : Wc;

    // One-time cache invalidate (L1 of this CU + L2 of this XCD): acquire RMW, agent scope.
    if (tid == 0)
        __hip_atomic_fetch_add(&flags[(size_t)(128 * 64 + j) * FLAG_STRIDE], 0u,
                               __ATOMIC_ACQ_REL, __HIP_MEMORY_SCOPE_AGENT);
    __syncthreads();

    // Fill B-fragments: lane l holds W_h[kk*32 + 8*(l>>4)+e][j*16 + (l&15)]
    {
        const int lc = l & 15, lh = l >> 4;
        for (int kk = 0; kk < 32; ++kk)
#pragma unroll
            for (int e = 0; e < 8; ++e) {
                int k = kk * 32 + lh * 8 + e;
                whf[w][kk][l][e] = f2bf(Wg[(size_t)(512 + k) * 1024 + j * 16 + lc]);
            }
    }
    __syncthreads();

    const int b = tid >> 4, hc = tid & 15;
    float cst = 0.f;
    // xz double-buffer: cz = step t, nz = step t+1 (issued early, consumed late)
    const float* xr0 = xz + (size_t)b * 4096 + j * 16 + hc;
    float cz0 = xr0[0], cz1 = xr0[1024], cz2 = xr0[2048], cz3 = xr0[3072];

    for (int t = 0; t < 128; ++t) {
        if (t > 0) {
            // ---- one wave polls step-(t-1) flags; lane l watches WG l's own line
            if (w == 0) {
                int spins = 0;
                while (true) {
                    u32 f = __hip_atomic_load(&flags[(size_t)((t - 1) * 64 + l) * FLAG_STRIDE],
                                              __ATOMIC_RELAXED, __HIP_MEMORY_SCOPE_SYSTEM);
                    if (__ballot(f != 0) == ~0ull) break;
                    __builtin_amdgcn_s_sleep(1);
                    if (++spins > (1 << 20)) break;   // safety bail
                }
            }
            __syncthreads();   // all waves gated on flags
        }
        // ---- issue next-step xz prefetch EARLY: latency hides under MFMA+gate math
        float nz0 = 0.f, nz1 = 0.f, nz2 = 0.f, nz3 = 0.f;
        if (t < 127) {
            const float* xr = xz + (size_t)((t + 1) * 16 + b) * 4096 + j * 16 + hc;
            nz0 = xr[0]; nz1 = xr[1024]; nz2 = xr[2048]; nz3 = xr[3072];
        }
        if (t > 0) {
            // ---- wave w computes gate w's 16x16 z-tile: z = h_{t-1} @ Wh_slice
            const u16* hrow = hs + (size_t)((t - 1) * 16 + (l & 15)) * 1024;
            bf16x8 a[32];
#pragma unroll
            for (int kk = 0; kk < 32; ++kk)
                a[kk] = *(const bf16x8*)(hrow + kk * 32 + (l >> 4) * 8);
            f32x4 zv = { 0.f, 0.f, 0.f, 0.f };
            f32x4 ac0 = zv, ac1 = zv, ac2 = zv, ac3 = zv;
#pragma unroll
            for (int kk = 0; kk < 32; kk += 4) {
                ac0 = __builtin_amdgcn_mfma_f32_16x16x32_bf16(a[kk + 0], *(const bf16x8*)&whf[w][kk + 0][l][0], ac0, 0, 0, 0);
                ac1 = __builtin_amdgcn_mfma_f32_16x16x32_bf16(a[kk + 1], *(const bf16x8*)&whf[w][kk + 1][l][0], ac1, 0, 0, 0);
                ac2 = __builtin_amdgcn_mfma_f32_16x16x32_bf16(a[kk + 2], *(const bf16x8*)&whf[w][kk + 2][l][0], ac2, 0, 0, 0);
                ac3 = __builtin_amdgcn_mfma_f32_16x16x32_bf16(a[kk + 3], *(const bf16x8*)&whf[w][kk + 3][l][0], ac3, 0, 0, 0);
            }
            f32x4 acc = (ac0 + ac1) + (ac2 + ac3);
#pragma unroll
            for (int r = 0; r < 4; ++r)
                zlds[w][(l >> 4) * 4 + r][l & 15] = acc[r];
        }
        __syncthreads();
        {
            float zi = cz0, zf = cz1, zo = cz2, zc = cz3;
            if (t > 0) {
                zi += zlds[0][b][hc]; zf += zlds[1][b][hc];
                zo += zlds[2][b][hc]; zc += zlds[3][b][hc];
            }
            float ig = 1.f / (1.f + __expf(-zi));
            float fg = 1.f / (1.f + __expf(-zf));
            float og = 1.f / (1.f + __expf(-zo));
            float gg = tanhf(zc);
            cst = fg * cst + ig * gg;
            float h = og * tanhf(cst);
            float hn = __shfl_xor(h, 1);          // partner lane's h (hc^1)
            if (!(l & 1)) {                        // even hc stores packed pair
                unsigned pk = (unsigned)f2bf(h) | ((unsigned)f2bf(hn) << 16);
                u32* dst = (u32*)hs + (((size_t)(t * 16 + b) * 1024 + j * 16 + hc) >> 1);
                __hip_atomic_store(dst, pk, __ATOMIC_RELAXED, __HIP_MEMORY_SCOPE_SYSTEM);
            }
        }
        // consume prefetch (loads issued ~whole step ago; wait is ~free here)
        cz0 = nz0; cz1 = nz1; cz2 = nz2; cz3 = nz3;
        __syncthreads();   // vmcnt(0) drain: all h stores at coherence point
        if (tid == 0)      // publish readiness on this WG's own cache line
            __hip_atomic_store(&flags[(size_t)(t * 64 + j) * FLAG_STRIDE], 1u,
                               __ATOMIC_RELAXED, __HIP_MEMORY_SCOPE_SYSTEM);
    }
}

extern "C" void kernel_launch(void* const* d_in, const int* in_sizes, int n_in,
                              void* d_out, int out_size, void* d_ws, size_t ws_size,
                              hipStream_t stream) {
    const int*   sent = (const int*)d_in[0];
    const float* emb  = (const float*)d_in[1];
    const float* W_i  = (const float*)d_in[2];
    const float* b_i  = (const float*)d_in[3];
    const float* W_f  = (const float*)d_in[4];
    const float* b_f  = (const float*)d_in[5];
    const float* W_o  = (const float*)d_in[6];
    const float* b_o  = (const float*)d_in[7];
    const float* W_c  = (const float*)d_in[8];
    const float* b_c  = (const float*)d_in[9];
    const float* W_hq = (const float*)d_in[10];
    const float* b_q  = (const float*)d_in[11];
    float* out = (float*)d_out;

    char* ws = (char*)d_ws;
    size_t off = 0;
    auto alloc = [&](size_t bytes) { void* p = ws + off; off += (bytes + 255) & ~255ull; return p; };
    size_t flag_bytes = (size_t)(128 * 64 + 64) * 16 * 4;   // one 64B line per flag
    u32*   flags = (u32*)alloc(flag_bytes);
    float* b4   = (float*)alloc((size_t)4096 * 4);
    u16*   xb   = (u16*)alloc((size_t)2048 * 512 * 2);
    u16*   wxt  = (u16*)alloc((size_t)4096 * 512 * 2);
    u16*   hs   = (u16*)alloc((size_t)2048 * 1024 * 2);
    float* xz   = (float*)alloc((size_t)2048 * 4096 * 4);
    u16*   whqt = (u16*)alloc((size_t)32000 * 1024 * 2);

    hipMemsetAsync(flags, 0, flag_bytes, stream);
    gather_embed<<<2048, 128, 0, stream>>>(sent, emb, xb);
    build_b4<<<16, 256, 0, stream>>>(b_i, b_f, b_o, b_c, b4);
    transpose_cvt<<<dim3(32, 16), 256, 0, stream>>>(W_i, 1024, wxt + (size_t)0 * 1024 * 512, 512);
    transpose_cvt<<<dim3(32, 16), 256, 0, stream>>>(W_f, 1024, wxt + (size_t)1 * 1024 * 512, 512);
    transpose_cvt<<<dim3(32, 16), 256, 0, stream>>>(W_o, 1024, wxt + (size_t)2 * 1024 * 512, 512);
    transpose_cvt<<<dim3(32, 16), 256, 0, stream>>>(W_c, 1024, wxt + (size_t)3 * 1024 * 512, 512);
    transpose_cvt<<<dim3(1000, 32), 256, 0, stream>>>(W_hq, 32000, whqt, 1024);
    // xz = X @ Wx + b4 : M=2048, K=512, N=4096
    gemm_bt<0><<<dim3(16, 32), 256, 0, stream>>>(xb, wxt, b4, xz, 512);
    // recurrence (writes hs)
    lstm_rec<<<64, 256, 0, stream>>>(hs, xz, W_i, W_f, W_o, W_c, flags);
    // out[b][v][t] = hs @ W_hq + b_q : M=2048 (b-major tiles), K=1024, N=32000
    gemm_bt<1><<<dim3(16, 250), 256, 0, stream>>>(hs, whqt, b_q, out, 1024);
}

// Round 6
// 729.190 us; speedup vs baseline: 2.1490x; 1.3710x over previous
//
#include <hip/hip_runtime.h>
#include <math.h>

typedef float f32x4 __attribute__((ext_vector_type(4)));
typedef short bf16x8 __attribute__((ext_vector_type(8)));
typedef unsigned short u16;
typedef unsigned int u32;
typedef unsigned long long u64;

__device__ __forceinline__ float bf2f(u16 v) {
    union { unsigned u; float f; } x; x.u = ((unsigned)v) << 16; return x.f;
}
__device__ __forceinline__ u16 f2bf(float f) {
    union { float f; unsigned u; } x; x.f = f;
    unsigned r = x.u + 0x7fff + ((x.u >> 16) & 1);   // RNE
    return (u16)(r >> 16);
}

// async global->LDS, 16B per lane. LDS dest is wave-uniform base + lane*16; global src per-lane.
__device__ __forceinline__ void gload_lds16(const u16* g, u16* l) {
    __builtin_amdgcn_global_load_lds(
        (const __attribute__((address_space(1))) void*)g,
        (__attribute__((address_space(3))) void*)l, 16, 0, 0);
}

// ---------------- embedding gather:  xb[t*16+b][e] = bf16(emb[sentence[b][t]][e])
__global__ void gather_embed(const int* __restrict__ sent, const float* __restrict__ emb,
                             u16* __restrict__ xb) {
    int row = blockIdx.x;             // t*16 + b
    int t = row >> 4, b = row & 15;
    int idx = sent[b * 128 + t];
    float4 v = ((const float4*)(emb + (size_t)idx * 512))[threadIdx.x];
    ushort4 s = { f2bf(v.x), f2bf(v.y), f2bf(v.z), f2bf(v.w) };
    ((ushort4*)(xb + (size_t)row * 512))[threadIdx.x] = s;
}

// ---------------- concat biases: b4[g*1024+c] = b_g[c]
__global__ void build_b4(const float* __restrict__ bi, const float* __restrict__ bf_,
                         const float* __restrict__ bo, const float* __restrict__ bc,
                         float* __restrict__ b4) {
    int i = blockIdx.x * 256 + threadIdx.x;   // 4096
    const float* p = (i < 1024) ? bi : (i < 2048) ? bf_ : (i < 3072) ? bo : bc;
    b4[i] = p[i & 1023];
}

// ---------------- tiled transpose + fp32->bf16:  out[C][R] = bf16(in[R][C])
__global__ void transpose_cvt(const float* __restrict__ in, int ldin,
                              u16* __restrict__ out, int ldout) {
    __shared__ float tile[32][33];
    int rt = blockIdx.y * 32, ct = blockIdx.x * 32;
    int tid = threadIdx.x;
    int r = tid >> 3, cq = (tid & 7) * 4;
    float4 v = *(const float4*)(in + (size_t)(rt + r) * ldin + ct + cq);
    tile[r][cq] = v.x; tile[r][cq + 1] = v.y; tile[r][cq + 2] = v.z; tile[r][cq + 3] = v.w;
    __syncthreads();
    int c = tid >> 3, rq = (tid & 7) * 4;
    ushort4 s = { f2bf(tile[rq][c]), f2bf(tile[rq + 1][c]),
                  f2bf(tile[rq + 2][c]), f2bf(tile[rq + 3][c]) };
    *(ushort4*)(out + (size_t)(ct + c) * ldout + rt + rq) = s;
}

// ---------------- GEMM: C = A[M][K](bf16) @ Bt[N][K](bf16)^T + bias
// MODE 0: A row-major, C row-major [M][4096] f32 (xz).
// MODE 1: A row r of tile = hs row (r*16 + blockIdx.x)  [b-major tiles];
//         out[b][v][t] f32 with float4 stores along t (coalesced).
template <int MODE>
__global__ __launch_bounds__(256) void gemm_bt(
    const u16* __restrict__ A, const u16* __restrict__ Bt,
    const float* __restrict__ bias, float* __restrict__ C, int K) {
    const int tid = threadIdx.x;
    const int l = tid & 63, w = tid >> 6;
    const int wr = w >> 1, wc = w & 1;
    const int m0 = blockIdx.x * 128, n0 = blockIdx.y * 128;
    __shared__ __align__(16) u16 As[128 * 64];
    __shared__ __align__(16) u16 Bs[128 * 64];

    f32x4 acc[4][4];
    f32x4 zz = { 0.f, 0.f, 0.f, 0.f };
#pragma unroll
    for (int i = 0; i < 4; i++)
#pragma unroll
        for (int j = 0; j < 4; j++) acc[i][j] = zz;

    const int nkt = K >> 6;
    for (int kt = 0; kt < nkt; ++kt) {
        __syncthreads();   // previous compute done before overwrite
#pragma unroll
        for (int i = 0; i < 4; i++) {
            int cbase = i * 256 + w * 64;      // wave-uniform LDS base (elements/8)
            int c = cbase + l, row = c >> 3, kc = c & 7;
            int arow = (MODE == 1) ? (row * 16 + (int)blockIdx.x) : (m0 + row);
            gload_lds16(A + (size_t)arow * K + kt * 64 + kc * 8, As + (size_t)cbase * 8);
            gload_lds16(Bt + (size_t)(n0 + row) * K + kt * 64 + kc * 8, Bs + (size_t)cbase * 8);
        }
        __syncthreads();   // drains vmcnt -> LDS ready
#pragma unroll
        for (int kk = 0; kk < 2; kk++) {
            bf16x8 af[4], bfv[4];
#pragma unroll
            for (int mi = 0; mi < 4; mi++)
                af[mi] = *(const bf16x8*)(As + (wr * 64 + mi * 16 + (l & 15)) * 64 + kk * 32 + (l >> 4) * 8);
#pragma unroll
            for (int ni = 0; ni < 4; ni++)
                bfv[ni] = *(const bf16x8*)(Bs + (wc * 64 + ni * 16 + (l & 15)) * 64 + kk * 32 + (l >> 4) * 8);
#pragma unroll
            for (int mi = 0; mi < 4; mi++)
#pragma unroll
                for (int ni = 0; ni < 4; ni++)
                    acc[mi][ni] = __builtin_amdgcn_mfma_f32_16x16x32_bf16(af[mi], bfv[ni], acc[mi][ni], 0, 0, 0);
        }
    }
    const int lr = l >> 4, lc = l & 15;
#pragma unroll
    for (int ni = 0; ni < 4; ni++) {
        int col = n0 + wc * 64 + ni * 16 + lc;
        float bv = bias[col];
#pragma unroll
        for (int mi = 0; mi < 4; mi++) {
            if (MODE == 0) {
#pragma unroll
                for (int r = 0; r < 4; r++) {
                    int row = m0 + wr * 64 + mi * 16 + lr * 4 + r;
                    C[(size_t)row * 4096 + col] = acc[mi][ni][r] + bv;
                }
            } else {
                int t0 = wr * 64 + mi * 16 + lr * 4;     // 4 consecutive t
                float4 st = { acc[mi][ni][0] + bv, acc[mi][ni][1] + bv,
                              acc[mi][ni][2] + bv, acc[mi][ni][3] + bv };
                *(float4*)(C + (size_t)blockIdx.x * 4096000 + (size_t)col * 128 + t0) = st;
            }
        }
    }
}

// ---------------- persistent LSTM recurrence: 64 WGs, each owns 16 h-cols.
// This round: W_h gate-slice lives in per-wave REGISTERS (128 VGPRs of B-frags);
// h_{t-1} is staged ONCE per WG into LDS via global_load_lds with pre-swizzled
// global source (linear LDS dest), fragments read back with the same XOR swizzle
// -> removes the 4x-redundant per-wave global h loads (2048 L1 line transactions
// per CU per step -> 512). Flag publish: per-wave vmcnt drain + LDS arrival
// counter; last wave publishes (no end-of-step barrier).
#define FLAG_STRIDE 16
__global__ __launch_bounds__(256, 1) void lstm_rec(
    u16* __restrict__ hs,          // [128*16][1024] bf16, row = t*16+b
    const float* __restrict__ xz,  // [128*16][4096] f32 (x-part + bias, precomputed)
    const float* __restrict__ Wi, const float* __restrict__ Wf,
    const float* __restrict__ Wo, const float* __restrict__ Wc,
    u32* __restrict__ flags) {     // [(128*64 + 64) * FLAG_STRIDE], zeroed
    __shared__ __align__(16) u16 hstage[16384];   // 32 KB: [row][slot] swizzled cols
    __shared__ float zlds[4][16][17];
    __shared__ u32 lds_cnt;
    const int j = blockIdx.x;            // h-col group: cols [j*16, j*16+16)
    const int tid = threadIdx.x;
    const int w = tid >> 6, l = tid & 63;
    const int row = l & 15, hi = l >> 4;
    const float* Wg = (w == 0) ? Wi : (w == 1) ? Wf : (w == 2) ? Wo : Wc;

    // One-time cache invalidate (cross-replay staleness): acquire RMW, agent scope.
    if (tid == 0) {
        lds_cnt = 0;
        __hip_atomic_fetch_add(&flags[(size_t)(128 * 64 + j) * FLAG_STRIDE], 0u,
                               __ATOMIC_ACQ_REL, __HIP_MEMORY_SCOPE_AGENT);
    }

    // W_h B-fragments in registers: wf[kk][e] = W_h[kk*32 + hi*8 + e][j*16 + row]
    bf16x8 wf[32];
    {
#pragma unroll
        for (int kk = 0; kk < 32; ++kk)
#pragma unroll
            for (int e = 0; e < 8; ++e)
                wf[kk][e] = f2bf(Wg[(size_t)(512 + kk * 32 + hi * 8 + e) * 1024 + j * 16 + row]);
    }
    __syncthreads();

    const int b = tid >> 4, hc = tid & 15;
    float cst = 0.f;
    const float* xr0 = xz + (size_t)b * 4096 + j * 16 + hc;
    float cz0 = xr0[0], cz1 = xr0[1024], cz2 = xr0[2048], cz3 = xr0[3072];

    for (int t = 0; t < 128; ++t) {
        if (t > 0) {
            // ---- one wave polls step-(t-1) flags; lane l watches WG l's own line
            if (w == 0) {
                int spins = 0;
                while (true) {
                    u32 f = __hip_atomic_load(&flags[(size_t)((t - 1) * 64 + l) * FLAG_STRIDE],
                                              __ATOMIC_RELAXED, __HIP_MEMORY_SCOPE_SYSTEM);
                    if (__ballot(f != 0) == ~0ull) break;
                    __builtin_amdgcn_s_sleep(1);
                    if (++spins > (1 << 20)) break;   // safety bail
                }
            }
            __syncthreads();   // all waves gated on flags
            // ---- stage h_{t-1} into LDS (32 KB), pre-swizzled source -> linear dest
            {
                const u16* hbase = hs + (size_t)(t - 1) * 16 * 1024;
#pragma unroll
                for (int q = 0; q < 8; ++q) {
                    int S = (w * 8 + q) * 64 + l;          // linear slot 0..2047
                    int sr = S >> 7, ss = S & 127;         // LDS row, slot
                    int c = (ss & ~7) | ((ss ^ sr) & 7);   // global 16B chunk
                    gload_lds16(hbase + sr * 1024 + c * 8, hstage + (size_t)(w * 8 + q) * 512);
                }
            }
        }
        // ---- issue next-step xz prefetch EARLY
        float nz0 = 0.f, nz1 = 0.f, nz2 = 0.f, nz3 = 0.f;
        if (t < 127) {
            const float* xr = xz + (size_t)((t + 1) * 16 + b) * 4096 + j * 16 + hc;
            nz0 = xr[0]; nz1 = xr[1024]; nz2 = xr[2048]; nz3 = xr[3072];
        }
        if (t > 0) {
            __syncthreads();   // vmcnt(0) drain -> hstage ready
            // ---- wave w: z-tile for gate w via MFMA, A-frags from swizzled LDS
            f32x4 zv = { 0.f, 0.f, 0.f, 0.f };
            f32x4 ac0 = zv, ac1 = zv, ac2 = zv, ac3 = zv;
#pragma unroll
            for (int kk = 0; kk < 32; kk += 4) {
#pragma unroll
                for (int u = 0; u < 4; ++u) {
                    int c = (kk + u) * 4 + hi;
                    int s = (c & ~7) | ((c ^ row) & 7);
                    bf16x8 a = *(const bf16x8*)(hstage + row * 1024 + s * 8);
                    f32x4& ac = (u == 0) ? ac0 : (u == 1) ? ac1 : (u == 2) ? ac2 : ac3;
                    ac = __builtin_amdgcn_mfma_f32_16x16x32_bf16(a, wf[kk + u], ac, 0, 0, 0);
                }
            }
            f32x4 acc = (ac0 + ac1) + (ac2 + ac3);
#pragma unroll
            for (int r = 0; r < 4; ++r)
                zlds[w][hi * 4 + r][row] = acc[r];
        }
        __syncthreads();   // zlds ready
        {
            float zi = cz0, zf = cz1, zo = cz2, zc = cz3;
            if (t > 0) {
                zi += zlds[0][b][hc]; zf += zlds[1][b][hc];
                zo += zlds[2][b][hc]; zc += zlds[3][b][hc];
            }
            float ig = 1.f / (1.f + __expf(-zi));
            float fg = 1.f / (1.f + __expf(-zf));
            float og = 1.f / (1.f + __expf(-zo));
            float gg = tanhf(zc);
            cst = fg * cst + ig * gg;
            float h = og * tanhf(cst);
            float hn = __shfl_xor(h, 1);          // partner lane's h (hc^1)
            if (!(l & 1)) {                        // even hc stores packed pair
                unsigned pk = (unsigned)f2bf(h) | ((unsigned)f2bf(hn) << 16);
                u32* dst = (u32*)hs + (((size_t)(t * 16 + b) * 1024 + j * 16 + hc) >> 1);
                __hip_atomic_store(dst, pk, __ATOMIC_RELAXED, __HIP_MEMORY_SCOPE_SYSTEM);
            }
        }
        cz0 = nz0; cz1 = nz1; cz2 = nz2; cz3 = nz3;
        // ---- per-wave drain + LDS arrival aggregation; last wave publishes flag
        asm volatile("s_waitcnt vmcnt(0)" ::: "memory");
        if (l == 0) {
            u32 old = atomicAdd(&lds_cnt, 1u);
            if (old == (u32)(4 * t + 3))
                __hip_atomic_store(&flags[(size_t)(t * 64 + j) * FLAG_STRIDE], 1u,
                                   __ATOMIC_RELAXED, __HIP_MEMORY_SCOPE_SYSTEM);
        }
    }
}

extern "C" void kernel_launch(void* const* d_in, const int* in_sizes, int n_in,
                              void* d_out, int out_size, void* d_ws, size_t ws_size,
                              hipStream_t stream) {
    const int*   sent = (const int*)d_in[0];
    const float* emb  = (const float*)d_in[1];
    const float* W_i  = (const float*)d_in[2];
    const float* b_i  = (const float*)d_in[3];
    const float* W_f  = (const float*)d_in[4];
    const float* b_f  = (const float*)d_in[5];
    const float* W_o  = (const float*)d_in[6];
    const float* b_o  = (const float*)d_in[7];
    const float* W_c  = (const float*)d_in[8];
    const float* b_c  = (const float*)d_in[9];
    const float* W_hq = (const float*)d_in[10];
    const float* b_q  = (const float*)d_in[11];
    float* out = (float*)d_out;

    char* ws = (char*)d_ws;
    size_t off = 0;
    auto alloc = [&](size_t bytes) { void* p = ws + off; off += (bytes + 255) & ~255ull; return p; };
    size_t flag_bytes = (size_t)(128 * 64 + 64) * 16 * 4;   // one 64B line per flag
    u32*   flags = (u32*)alloc(flag_bytes);
    float* b4   = (float*)alloc((size_t)4096 * 4);
    u16*   xb   = (u16*)alloc((size_t)2048 * 512 * 2);
    u16*   wxt  = (u16*)alloc((size_t)4096 * 512 * 2);
    u16*   hs   = (u16*)alloc((size_t)2048 * 1024 * 2);
    float* xz   = (float*)alloc((size_t)2048 * 4096 * 4);
    u16*   whqt = (u16*)alloc((size_t)32000 * 1024 * 2);

    hipMemsetAsync(flags, 0, flag_bytes, stream);
    gather_embed<<<2048, 128, 0, stream>>>(sent, emb, xb);
    build_b4<<<16, 256, 0, stream>>>(b_i, b_f, b_o, b_c, b4);
    transpose_cvt<<<dim3(32, 16), 256, 0, stream>>>(W_i, 1024, wxt + (size_t)0 * 1024 * 512, 512);
    transpose_cvt<<<dim3(32, 16), 256, 0, stream>>>(W_f, 1024, wxt + (size_t)1 * 1024 * 512, 512);
    transpose_cvt<<<dim3(32, 16), 256, 0, stream>>>(W_o, 1024, wxt + (size_t)2 * 1024 * 512, 512);
    transpose_cvt<<<dim3(32, 16), 256, 0, stream>>>(W_c, 1024, wxt + (size_t)3 * 1024 * 512, 512);
    transpose_cvt<<<dim3(1000, 32), 256, 0, stream>>>(W_hq, 32000, whqt, 1024);
    // xz = X @ Wx + b4 : M=2048, K=512, N=4096
    gemm_bt<0><<<dim3(16, 32), 256, 0, stream>>>(xb, wxt, b4, xz, 512);
    // recurrence (writes hs)
    lstm_rec<<<64, 256, 0, stream>>>(hs, xz, W_i, W_f, W_o, W_c, flags);
    // out[b][v][t] = hs @ W_hq + b_q : M=2048 (b-major tiles), K=1024, N=32000
    gemm_bt<1><<<dim3(16, 250), 256, 0, stream>>>(hs, whqt, b_q, out, 1024);
}